// Round 10
// baseline (508.614 us; speedup 1.0000x reference)
//
#include <hip/hip_runtime.h>
#include <hip/hip_bf16.h>
#include <math.h>

#define NN 512   // hidden states
#define MM 256   // timesteps / emission symbols
#define BB 128   // batch

typedef float        f32x4 __attribute__((ext_vector_type(4)));
typedef unsigned int u32;
typedef u32          u32x2 __attribute__((ext_vector_type(2)));
typedef unsigned long long u64;

#define LOG16F 2.772588722239781f

__device__ __forceinline__ float wave_max(float v) {
#pragma unroll
    for (int o = 32; o > 0; o >>= 1) v = fmaxf(v, __shfl_xor(v, o));
    return v;
}
__device__ __forceinline__ float wave_sum(float v) {
#pragma unroll
    for (int o = 32; o > 0; o >>= 1) v += __shfl_xor(v, o);
    return v;
}

// ---------------- preprocessing ----------------

// Column-wise logsumexp of T (log_softmax axis=0 denominator). grid 8 x 64.
__global__ void k_col_lse(const float* __restrict__ T, float* __restrict__ c) {
    int k = blockIdx.x * 64 + threadIdx.x;
    float m = -INFINITY, s = 0.f;
    for (int i = 0; i < NN; ++i) {
        float x = T[i * NN + k];
        if (x > m) { s = s * __expf(m - x) + 1.f; m = x; }
        else       { s += __expf(x - m); }
    }
    c[k] = m + __logf(s);
}

// Row max: M[i] = max_k(T[i,k]-c[k]) - log(64). grid 512 x 64.
__global__ void k_rowM(const float* __restrict__ T, const float* __restrict__ c,
                       float* __restrict__ M) {
    int i = blockIdx.x, j = threadIdx.x;
    float mx = -INFINITY;
#pragma unroll
    for (int d = 0; d < 8; ++d) {
        int k = j * 8 + d;
        mx = fmaxf(mx, T[i * NN + k] - c[k]);
    }
    mx = wave_max(mx);
    if (j == 0) M[i] = mx - __logf(64.f);
}

// C_M = max_i M[i]. grid 1 x 512.
__global__ void k_cm(const float* __restrict__ M, float* __restrict__ CM) {
    __shared__ float red[8];
    int i = threadIdx.x;
    float wm = wave_max(M[i]);
    if ((i & 63) == 0) red[i >> 6] = wm;
    __syncthreads();
    if (i == 0) {
        float m = red[0];
#pragma unroll
        for (int j = 1; j < 8; ++j) m = fmaxf(m, red[j]);
        CM[0] = m;
    }
}

// log-softmax of priors folded with EX normalization:
// lp2[i] = exp(lp[i] - M[i] + C_M + log16). grid 1 x 512.
__global__ void k_priors(const float* __restrict__ pr, const float* __restrict__ M,
                         const float* __restrict__ CM, float* __restrict__ lp2) {
    __shared__ float red[8];
    int i = threadIdx.x;
    float x = pr[i];
    float wm = wave_max(x);
    if ((i & 63) == 0) red[i >> 6] = wm;
    __syncthreads();
    float m = red[0];
#pragma unroll
    for (int j = 1; j < 8; ++j) m = fmaxf(m, red[j]);
    float e = __expf(x - m);
    float ws = wave_sum(e);
    __syncthreads();
    if ((i & 63) == 0) red[i >> 6] = ws;
    __syncthreads();
    float S = red[0];
#pragma unroll
    for (int j = 1; j < 8; ++j) S += red[j];
    float lp = x - (m + __logf(S));
    lp2[i] = __expf(lp - M[i] + CM[0] + LOG16F);
}

// Pack P into fp8 MFMA A-fragments, scaled x64 (row max -> 64).
// Fragment (tile,kc): lane l holds 8 bytes = P[row=tile*16+(l&15),
// k=kc*32+(l>>4)*8+j], j ascending. Stored as u64 at PA8[(tile*16+kc)*64+l].
__global__ void k_packA(const float* __restrict__ T, const float* __restrict__ c,
                        const float* __restrict__ M, u32* __restrict__ PA) {
    int blk = blockIdx.x, l = threadIdx.x;
    int tile = blk >> 4, kc = blk & 15;
    int row = tile * 16 + (l & 15);
    int kb  = kc * 32 + (l >> 4) * 8;
    float Mi = M[row];                    // = rowmax - log64
    float p[8];
#pragma unroll
    for (int j = 0; j < 8; ++j)
        p[j] = __expf(T[row * NN + kb + j] - c[kb + j] - Mi);   // <= 64
    int d0 = 0, d1 = 0;
    d0 = __builtin_amdgcn_cvt_pk_fp8_f32(p[0], p[1], d0, false);
    d0 = __builtin_amdgcn_cvt_pk_fp8_f32(p[2], p[3], d0, true);
    d1 = __builtin_amdgcn_cvt_pk_fp8_f32(p[4], p[5], d1, false);
    d1 = __builtin_amdgcn_cvt_pk_fp8_f32(p[6], p[7], d1, true);
    u32x2 st = { (u32)d0, (u32)d1 };
    *(u32x2*)(PA + ((size_t)blk * 64 + l) * 2) = st;
}

// Row i of E: log-softmax + fold the scan's exp:
// EX[m*NN+i] = exp(logE[i,m] + M[i] - C_M - log16). grid 512 x 64.
__global__ void k_rowEX(const float* __restrict__ E, const float* __restrict__ M,
                        const float* __restrict__ CM, float* __restrict__ EX) {
    int i = blockIdx.x, j = threadIdx.x;
    float v[4];
    float mx = -INFINITY;
#pragma unroll
    for (int d = 0; d < 4; ++d) {
        v[d] = E[i * MM + j * 4 + d];
        mx = fmaxf(mx, v[d]);
    }
    mx = wave_max(mx);
    float s = 0.f;
#pragma unroll
    for (int d = 0; d < 4; ++d) s += __expf(v[d] - mx);
    s = wave_sum(s);
    float lse = mx + __logf(s);
    float add = M[i] - CM[0] - LOG16F - lse;
#pragma unroll
    for (int d = 0; d < 4; ++d)
        EX[(size_t)(j * 4 + d) * NN + i] = __expf(v[d] + add);
}

// ---------------- the scan (MFMA, fresh scale, EX-precomputed) ----------------
// One block per batch, 512 threads = 8 waves. Wave w owns i-tiles w*4..w*4+3.
// P fp8 A-frags resident in AGPR/VGPR. Publish u-hat = e_t * 16/S_t (FRESH,
// r7-proven numerics; u-hat <= 16, no clamps). Per-step exp is precomputed
// (EX table): step = {EX load || MFMA} -> mul -> sum -> B1 -> S,log,out ->
// quantize publish -> B2. Omega: K_{t+1} = K_t + C_M + lS_t; out_t = K_t+lS_t.
__global__ __launch_bounds__(512, 2) void k_scan(
        const int* __restrict__ obs, const float* __restrict__ lp2,
        const float* __restrict__ CM, const u32* __restrict__ PAu,
        const float* __restrict__ EX, float* __restrict__ out) {
    int b = blockIdx.x, tid = threadIdx.x;
    int w = tid >> 6, l = tid & 63;
    int hi16 = l >> 4;                    // 0..3
    int r4 = hi16 * 4;                    // row group within a 16-row tile
    __shared__ unsigned char us8[NN] __attribute__((aligned(16)));
    __shared__ float rB[8] __attribute__((aligned(16)));
    __shared__ int obs_s[MM];
    if (tid < MM) obs_s[tid] = obs[b * MM + tid];

    // --- stage A-fragments: 64 x u64 per lane (4 tiles x 16 k-chunks) ---
    const u64* PA8 = (const u64*)PAu;
    u64 pa[64];
#pragma unroll
    for (int ti = 0; ti < 4; ++ti)
#pragma unroll
        for (int kc = 0; kc < 16; ++kc)
            pa[ti * 16 + kc] = PA8[(size_t)(((w * 4 + ti) * 16 + kc)) * 64 + l];
#pragma unroll
    for (int q = 0; q < 64; ++q) asm volatile("" : "+v"(pa[q]));

    float C_M = CM[0];
    __syncthreads();                      // obs_s ready

    // ---- t = 0: e = EX[o0] * lp2  (= exp(em0 + log_priors)) ----
    int o0 = obs_s[0];
    f32x4 e4[4];
    float loc = 0.f;
#pragma unroll
    for (int ti = 0; ti < 4; ++ti) {
        f32x4 ex  = *(const f32x4*)(EX  + (size_t)o0 * NN + (w * 4 + ti) * 16 + r4);
        f32x4 lpv = *(const f32x4*)(lp2 + (w * 4 + ti) * 16 + r4);
#pragma unroll
        for (int r = 0; r < 4; ++r) {
            float e = ex[r] * lpv[r];
            e4[ti][r] = e; loc += e;
        }
    }
    loc += __shfl_xor(loc, 16);
    loc += __shfl_xor(loc, 32);
    if (l == 0) rB[w] = loc;
    __syncthreads();                      // B1
    f32x4 sv0 = *(const f32x4*)rB;
    f32x4 sv1 = *(const f32x4*)(rB + 4);
    float S = (sv0[0] + sv0[1]) + (sv0[2] + sv0[3])
            + (sv1[0] + sv1[1]) + (sv1[2] + sv1[3]);
    S = fmaxf(S, 1e-35f);
    float lS = __logf(S);
    if (tid == 0) out[(size_t)b * MM + 0] = lS;
    float sc = __builtin_amdgcn_rcpf(S) * 16.f;
    if ((l & 15) == 0) {
#pragma unroll
        for (int ti = 0; ti < 4; ++ti) {
            int d = 0;
            d = __builtin_amdgcn_cvt_pk_fp8_f32(e4[ti][0] * sc, e4[ti][1] * sc, d, false);
            d = __builtin_amdgcn_cvt_pk_fp8_f32(e4[ti][2] * sc, e4[ti][3] * sc, d, true);
            *(u32*)&us8[(w * 4 + ti) * 16 + r4] = (u32)d;
        }
    }
    __syncthreads();                      // B2: us8 ready
    float K = C_M + lS;                   // Omega_1

    // ---- main scan t >= 1: fresh scale, 2 barriers ----
#pragma unroll 1
    for (int t = 1; t < MM; ++t) {
        int o = obs_s[t];
        f32x4 ex[4];
#pragma unroll
        for (int ti = 0; ti < 4; ++ti)
            ex[ti] = *(const f32x4*)(EX + (size_t)o * NN + (w * 4 + ti) * 16 + r4);

        const unsigned char* ub = us8;
        f32x4 aA0 = {0.f,0.f,0.f,0.f}, aA1 = {0.f,0.f,0.f,0.f};
        f32x4 aA2 = {0.f,0.f,0.f,0.f}, aA3 = {0.f,0.f,0.f,0.f};
        f32x4 aB0 = {0.f,0.f,0.f,0.f}, aB1 = {0.f,0.f,0.f,0.f};
        f32x4 aB2 = {0.f,0.f,0.f,0.f}, aB3 = {0.f,0.f,0.f,0.f};
        __builtin_amdgcn_s_setprio(1);
#pragma unroll
        for (int kp = 0; kp < 8; ++kp) {   // 8 chains of depth 8
            int kc0 = 2 * kp, kc1 = 2 * kp + 1;
            u64 b0 = *(const u64*)(ub + kc0 * 32 + hi16 * 8);
            u64 b1 = *(const u64*)(ub + kc1 * 32 + hi16 * 8);
            aA0 = __builtin_amdgcn_mfma_f32_16x16x32_fp8_fp8((long)pa[0*16+kc0], (long)b0, aA0, 0, 0, 0);
            aA1 = __builtin_amdgcn_mfma_f32_16x16x32_fp8_fp8((long)pa[1*16+kc0], (long)b0, aA1, 0, 0, 0);
            aA2 = __builtin_amdgcn_mfma_f32_16x16x32_fp8_fp8((long)pa[2*16+kc0], (long)b0, aA2, 0, 0, 0);
            aA3 = __builtin_amdgcn_mfma_f32_16x16x32_fp8_fp8((long)pa[3*16+kc0], (long)b0, aA3, 0, 0, 0);
            aB0 = __builtin_amdgcn_mfma_f32_16x16x32_fp8_fp8((long)pa[0*16+kc1], (long)b1, aB0, 0, 0, 0);
            aB1 = __builtin_amdgcn_mfma_f32_16x16x32_fp8_fp8((long)pa[1*16+kc1], (long)b1, aB1, 0, 0, 0);
            aB2 = __builtin_amdgcn_mfma_f32_16x16x32_fp8_fp8((long)pa[2*16+kc1], (long)b1, aB2, 0, 0, 0);
            aB3 = __builtin_amdgcn_mfma_f32_16x16x32_fp8_fp8((long)pa[3*16+kc1], (long)b1, aB3, 0, 0, 0);
        }
        __builtin_amdgcn_s_setprio(0);
        f32x4 sacc[4] = { aA0 + aB0, aA1 + aB1, aA2 + aB2, aA3 + aB3 };

        loc = 0.f;
#pragma unroll
        for (int ti = 0; ti < 4; ++ti)
#pragma unroll
            for (int r = 0; r < 4; ++r) {
                float e = ex[ti][r] * sacc[ti][r];
                e4[ti][r] = e; loc += e;
            }
        loc += __shfl_xor(loc, 16);
        loc += __shfl_xor(loc, 32);
        if (l == 0) rB[w] = loc;
        __syncthreads();                  // B1: rB ready (us8 reads done too)
        sv0 = *(const f32x4*)rB;
        sv1 = *(const f32x4*)(rB + 4);
        S = (sv0[0] + sv0[1]) + (sv0[2] + sv0[3])
          + (sv1[0] + sv1[1]) + (sv1[2] + sv1[3]);
        S = fmaxf(S, 1e-35f);
        float lSn = __logf(S);
        if (tid == 0) out[(size_t)b * MM + t] = K + lSn;
        K += C_M + lSn;                   // Omega_{t+1} (fresh sigma_t)
        sc = __builtin_amdgcn_rcpf(S) * 16.f;
        if ((l & 15) == 0) {
#pragma unroll
            for (int ti = 0; ti < 4; ++ti) {
                int d = 0;
                d = __builtin_amdgcn_cvt_pk_fp8_f32(e4[ti][0] * sc, e4[ti][1] * sc, d, false);
                d = __builtin_amdgcn_cvt_pk_fp8_f32(e4[ti][2] * sc, e4[ti][3] * sc, d, true);
                *(u32*)&us8[(w * 4 + ti) * 16 + r4] = (u32)d;
            }
        }
        __syncthreads();                  // B2: us8 ready for next step
    }
}

extern "C" void kernel_launch(void* const* d_in, const int* in_sizes, int n_in,
                              void* d_out, int out_size, void* d_ws, size_t ws_size,
                              hipStream_t stream) {
    const int*   obs = (const int*)d_in[0];
    const float* pri = (const float*)d_in[1];
    const float* T   = (const float*)d_in[2];
    const float* E   = (const float*)d_in[3];
    float* out = (float*)d_out;
    char* ws = (char*)d_ws;

    float* c   = (float*)(ws + 0);
    float* lp2 = (float*)(ws + 2048);
    float* M   = (float*)(ws + 4096);
    float* CM  = (float*)(ws + 6144);
    u32*   PA  = (u32*)(ws + 8192);                       // 256 KB fp8 A-frags
    float* EX  = (float*)(ws + 8192 + 256 * 1024);        // 512 KB

    k_col_lse<<<8,   64, 0, stream>>>(T, c);
    k_rowM   <<<512, 64, 0, stream>>>(T, c, M);
    k_cm     <<<1,  512, 0, stream>>>(M, CM);
    k_priors <<<1,  512, 0, stream>>>(pri, M, CM, lp2);
    k_packA  <<<512, 64, 0, stream>>>(T, c, M, PA);
    k_rowEX  <<<512, 64, 0, stream>>>(E, M, CM, EX);
    k_scan   <<<BB, 512, 0, stream>>>(obs, lp2, CM, PA, EX, out);
}